// Round 4
// baseline (617.084 us; speedup 1.0000x reference)
//
#include <hip/hip_runtime.h>
#include <hip/hip_bf16.h>
#include <cstdint>
#include <cstddef>

// Problem constants
#define T_TOK 4096
#define D_DIM 1024
#define E_EXP 8
#define KSEL 2
#define CAP 1280      // floor(2*1.25*4096/8) = 1280
#define HID_DIM 4096

typedef __attribute__((ext_vector_type(8))) __bf16 bf16x8;
typedef __attribute__((ext_vector_type(8))) unsigned short ushort8;
typedef __attribute__((ext_vector_type(4))) float floatx4;
typedef __attribute__((ext_vector_type(4))) unsigned int uintx4;

__device__ __forceinline__ unsigned short f2bf(float f) {
  unsigned int u = __builtin_bit_cast(unsigned int, f);
  u = (u + 0x7FFFu + ((u >> 16) & 1u)) >> 16;  // RNE
  return (unsigned short)u;
}
__device__ __forceinline__ float bf2f(unsigned short h) {
  unsigned int u = ((unsigned int)h) << 16;
  return __builtin_bit_cast(float, u);
}

// async global->LDS, 16B per lane; lds dest = wave-uniform base + lane*16
__device__ __forceinline__ void async16(const unsigned short* g, unsigned short* l) {
  __builtin_amdgcn_global_load_lds(
      (const __attribute__((address_space(1))) unsigned int*)g,
      (__attribute__((address_space(3))) unsigned int*)l, 16, 0, 0);
}

// ---------------- Router: logits, top-2, softmax probs, per-block loss partials ----------------
__global__ void router_kernel(const float* __restrict__ x, const float* __restrict__ wg,
                              int* __restrict__ top1, int* __restrict__ top2,
                              float* __restrict__ p0, float* __restrict__ p1,
                              float* __restrict__ lps_part, float* __restrict__ lz_part) {
  __shared__ float lps[E_EXP];
  __shared__ float lz;
  if (threadIdx.x < E_EXP) lps[threadIdx.x] = 0.f;
  if (threadIdx.x == 0) lz = 0.f;
  __syncthreads();
  int wave = threadIdx.x >> 6;
  int lane = threadIdx.x & 63;
  int t = blockIdx.x * 4 + wave;
  const float4* xr = (const float4*)(x + (size_t)t * D_DIM);
  float acc[E_EXP];
#pragma unroll
  for (int e = 0; e < E_EXP; ++e) acc[e] = 0.f;
#pragma unroll
  for (int j = 0; j < D_DIM / 256; ++j) {        // 4 iters, float4 x loads (G13)
    int i4 = lane + 64 * j;                      // float4 index
    float4 xv = xr[i4];
    const float4* wr = (const float4*)(wg + (size_t)i4 * 4 * E_EXP);  // rows 4*i4 .. 4*i4+3
    float4 w0 = wr[0], w1 = wr[1];               // row 4*i4
    float4 w2 = wr[2], w3 = wr[3];               // row 4*i4+1
    float4 w4 = wr[4], w5 = wr[5];               // row 4*i4+2
    float4 w6 = wr[6], w7 = wr[7];               // row 4*i4+3
    acc[0] += xv.x * w0.x + xv.y * w2.x + xv.z * w4.x + xv.w * w6.x;
    acc[1] += xv.x * w0.y + xv.y * w2.y + xv.z * w4.y + xv.w * w6.y;
    acc[2] += xv.x * w0.z + xv.y * w2.z + xv.z * w4.z + xv.w * w6.z;
    acc[3] += xv.x * w0.w + xv.y * w2.w + xv.z * w4.w + xv.w * w6.w;
    acc[4] += xv.x * w1.x + xv.y * w3.x + xv.z * w5.x + xv.w * w7.x;
    acc[5] += xv.x * w1.y + xv.y * w3.y + xv.z * w5.y + xv.w * w7.y;
    acc[6] += xv.x * w1.z + xv.y * w3.z + xv.z * w5.z + xv.w * w7.z;
    acc[7] += xv.x * w1.w + xv.y * w3.w + xv.z * w5.w + xv.w * w7.w;
  }
#pragma unroll
  for (int e = 0; e < E_EXP; ++e) {
#pragma unroll
    for (int s = 32; s > 0; s >>= 1) acc[e] += __shfl_xor(acc[e], s);
  }
  if (lane == 0) {
    int i1 = 0; float v1 = acc[0];
    for (int e = 1; e < E_EXP; ++e) if (acc[e] > v1) { v1 = acc[e]; i1 = e; }
    int i2 = -1; float v2 = -1e30f;
    for (int e = 0; e < E_EXP; ++e) if (e != i1 && acc[e] > v2) { v2 = acc[e]; i2 = e; }
    top1[t] = i1; top2[t] = i2;
    float dexp = expf(v2 - v1);            // softmax over the two kept logits
    p0[t] = 1.f / (1.f + dexp);
    p1[t] = dexp / (1.f + dexp);
    float pe[E_EXP]; float ssum = 0.f;
    for (int e = 0; e < E_EXP; ++e) { pe[e] = expf(acc[e] - v1); ssum += pe[e]; }
    float lse = logf(ssum) + v1;
    atomicAdd(&lz, lse * lse);             // LDS atomics only
    float inv = 1.f / ssum;
    for (int e = 0; e < E_EXP; ++e) atomicAdd(&lps[e], pe[e] * inv);
  }
  __syncthreads();
  if (threadIdx.x < E_EXP) lps_part[(size_t)blockIdx.x * E_EXP + threadIdx.x] = lps[threadIdx.x];
  if (threadIdx.x == 0) lz_part[blockIdx.x] = lz;
}

// -------- Deterministic k-major capacity scan (1 block, 256 thr x 16 tokens) --------
// Also: reduces router loss partials -> probsum/zsum, and fills unused slots with -1.
__global__ void scan_kernel(const int* __restrict__ top1, const int* __restrict__ top2,
                            const float* __restrict__ lps_part, const float* __restrict__ lz_part,
                            int* __restrict__ rank0, int* __restrict__ rank1,
                            int* __restrict__ slot_token, int* __restrict__ cntk,
                            float* __restrict__ probsum, float* __restrict__ zsum) {
  __shared__ int sc[256][E_EXP];
  __shared__ float red[4][E_EXP + 1];
  int c = threadIdx.x;

  // ---- loss-partial reduction (1024 blocks worth) ----
  {
    float myz = 0.f;
    float myp[E_EXP];
#pragma unroll
    for (int e = 0; e < E_EXP; ++e) myp[e] = 0.f;
    for (int i = c; i < T_TOK / 4; i += 256) {
      myz += lz_part[i];
#pragma unroll
      for (int e = 0; e < E_EXP; ++e) myp[e] += lps_part[(size_t)i * E_EXP + e];
    }
#pragma unroll
    for (int s = 32; s > 0; s >>= 1) {
      myz += __shfl_xor(myz, s);
#pragma unroll
      for (int e = 0; e < E_EXP; ++e) myp[e] += __shfl_xor(myp[e], s);
    }
    int wv = c >> 6, ln = c & 63;
    if (ln == 0) {
      red[wv][E_EXP] = myz;
      for (int e = 0; e < E_EXP; ++e) red[wv][e] = myp[e];
    }
    __syncthreads();
    if (c == 0) {
      float z = red[0][E_EXP] + red[1][E_EXP] + red[2][E_EXP] + red[3][E_EXP];
      zsum[0] = z;
      for (int e = 0; e < E_EXP; ++e)
        probsum[e] = red[0][e] + red[1][e] + red[2][e] + red[3][e];
    }
  }

  int e0l[16], e1l[16];
  int c0[E_EXP], c1[E_EXP];
#pragma unroll
  for (int e = 0; e < E_EXP; ++e) { c0[e] = 0; c1[e] = 0; }
#pragma unroll
  for (int j = 0; j < 16; ++j) {
    int t = c * 16 + j;
    int a = top1[t]; int b = top2[t];
    e0l[j] = a; e1l[j] = b;
    c0[a]++; c1[b]++;
  }
  for (int e = 0; e < E_EXP; ++e) sc[c][e] = c0[e];
  __syncthreads();
  for (int s = 1; s < 256; s <<= 1) {
    int tmp[E_EXP];
    if (c >= s) { for (int e = 0; e < E_EXP; ++e) tmp[e] = sc[c - s][e]; }
    __syncthreads();
    if (c >= s) { for (int e = 0; e < E_EXP; ++e) sc[c][e] += tmp[e]; }
    __syncthreads();
  }
  int off0[E_EXP], tot0[E_EXP];
  for (int e = 0; e < E_EXP; ++e) {
    off0[e] = (c > 0) ? sc[c - 1][e] : 0;
    tot0[e] = sc[255][e];
  }
  __syncthreads();
  for (int e = 0; e < E_EXP; ++e) sc[c][e] = c1[e];
  __syncthreads();
  for (int s = 1; s < 256; s <<= 1) {
    int tmp[E_EXP];
    if (c >= s) { for (int e = 0; e < E_EXP; ++e) tmp[e] = sc[c - s][e]; }
    __syncthreads();
    if (c >= s) { for (int e = 0; e < E_EXP; ++e) sc[c][e] += tmp[e]; }
    __syncthreads();
  }
  int off1[E_EXP], tot1[E_EXP];
  for (int e = 0; e < E_EXP; ++e) {
    off1[e] = (c > 0) ? sc[c - 1][e] : 0;
    tot1[e] = sc[255][e];
  }
  int run[E_EXP];
  for (int e = 0; e < E_EXP; ++e) run[e] = off0[e];
#pragma unroll
  for (int j = 0; j < 16; ++j) {
    int t = c * 16 + j;
    int e = e0l[j];
    int r = run[e]++;
    if (r < CAP) { rank0[t] = r; slot_token[e * CAP + r] = t; } else rank0[t] = -1;
  }
  for (int e = 0; e < E_EXP; ++e) run[e] = tot0[e] + off1[e];
#pragma unroll
  for (int j = 0; j < 16; ++j) {
    int t = c * 16 + j;
    int e = e1l[j];
    int r = run[e]++;
    if (r < CAP) { rank1[t] = r; slot_token[e * CAP + r] = t; } else rank1[t] = -1;
  }
  // fill unused slots with -1 (replaces slot memset); cnt known to every thread
  for (int e = 0; e < E_EXP; ++e) {
    int tot = tot0[e] + tot1[e];
    int cnt = tot < CAP ? tot : CAP;
    for (int r = cnt + c; r < CAP; r += 256) slot_token[e * CAP + r] = -1;
    if (c == 0) cntk[e] = cnt;
  }
}

// ---------------- Dispatch: gather tokens into expert batches (bf16) ----------------
__global__ void dispatch_kernel(const float* __restrict__ x, const int* __restrict__ slot_token,
                                unsigned short* __restrict__ batch) {
  int slot = blockIdx.x;  // e*CAP + c
  int t = slot_token[slot];
  int d = threadIdx.x * 4;
  ushort4 o;
  if (t >= 0) {
    float4 v = *(const float4*)(x + (size_t)t * D_DIM + d);
    o.x = f2bf(v.x); o.y = f2bf(v.y); o.z = f2bf(v.z); o.w = f2bf(v.w);
  } else {
    o.x = 0; o.y = 0; o.z = 0; o.w = 0;
  }
  *(ushort4*)(batch + (size_t)slot * D_DIM + d) = o;
}

// ------------- bf16 MFMA GEMM with FUSED fp32 weight transpose+convert in B-staging -------------
// C[M][N] = A[M][KD] * Wnat^T, where A is bf16 [M][KD] (k-contiguous) and Wnat is the UNTRANSPOSED
// fp32 weight [KD][NN] (n-contiguous) read directly -- no separate transpose kernel, no W buffer.
// 128x128 tile, BK=32, 4 waves x (4x4 16x16x32 MFMA).  Per K-step:
//   A: async16 global_load_lds x2/thread into swizzled As (unchanged from proven kernel).
//   B: reg-staged. Thread owns row n=tid&127, k-blocks {c,c+2} (c=tid>>7).  16 scalar fp32 loads
//      (per instr: 64 consecutive n = 256B coalesced), f2bf+pack, 2x ds_write_b128 into physical
//      slot g^((n>>1)&3) -- IDENTICAL layout to the old async16 staging, so fragment reads
//      (0 measured bank conflicts) are untouched.  b128 scatter banks: lane groups (n mod 8) ->
//      8 distinct bank-quads covering all 32 banks -> conflict-free.
//   B(k+1) prefetched into regs BEFORE the barrier: HBM latency hides under the vmcnt(0) drain
//      that the barrier already performs for A's global_load_lds.  2-barrier structure preserved.
// Grid 1D; bid%8 = expert = XCD pinning (L2 locality), as before.
template <int KD, int NN, int NG_TILES, bool GELU>
__global__ __launch_bounds__(256) void gemm_fused(const unsigned short* __restrict__ A,
                                                  const float* __restrict__ Wnat,
                                                  unsigned short* __restrict__ Cd,
                                                  const int* __restrict__ cntk) {
  constexpr int MT = CAP / 128;            // 10 m-tiles
  constexpr int GRP = MT * NG_TILES;       // blocks per (expert, n-group)
  int bid = blockIdx.x;
  int e = bid & 7;                          // XCD-pinned expert
  int slot = bid >> 3;
  int ng = slot / GRP;
  int rem = slot - ng * GRP;
  int mm = rem / NG_TILES;
  int nw = rem - mm * NG_TILES;
  int m0 = mm * 128;
  int n0 = (ng * NG_TILES + nw) * 128;
  if (m0 >= cntk[e]) return;               // skip tiles past kept-token count
  const unsigned short* Ae = A + (size_t)e * CAP * KD;
  const float* Be = Wnat + (size_t)e * KD * NN;   // natural [KD][NN] fp32
  unsigned short* Ce = Cd + (size_t)e * CAP * NN;
  __shared__ unsigned short As[128 * 32];
  __shared__ unsigned short Bs[128 * 32];
  int tid = threadIdx.x;
  int lane = tid & 63;
  int wv = tid >> 6;
  int wm = (wv & 1) * 64;
  int wn = (wv >> 1) * 64;
  int mrow = lane & 15;
  int kqb = lane >> 4;                      // 16B-block index of the k-fragment
  int sx = (mrow >> 1) & 3;                 // row swizzle key (16-aligned row bases)
  int kb = (kqb ^ sx) * 8;                  // element offset of swizzled block

  // B reg-staging geometry
  const int nB = tid & 127;                 // owned B row (n within tile)
  const int cb0 = tid >> 7;                 // first owned k-block (0 or 1); second is cb0+2
  const int swB = (nB >> 1) & 3;            // swizzle key for this row
  unsigned short* bdst0 = &Bs[(nB * 4 + (cb0 ^ swB)) * 8];
  unsigned short* bdst1 = &Bs[(nB * 4 + ((cb0 + 2) ^ swB)) * 8];
  const float* bsrc = Be + n0 + nB;         // column base; row offset added per load

  floatx4 acc[4][4];
#pragma unroll
  for (int i = 0; i < 4; ++i)
#pragma unroll
    for (int j = 0; j < 4; ++j) {
      floatx4 z = {0.f, 0.f, 0.f, 0.f};
      acc[i][j] = z;
    }

  // prologue: prefetch B(k=0) into regs
  float bpre[16];
  {
    const float* p0 = bsrc + (size_t)(cb0 * 8) * NN;
    const float* p1 = bsrc + (size_t)(cb0 * 8 + 16) * NN;
#pragma unroll
    for (int j = 0; j < 8; ++j) {
      bpre[j]     = p0[(size_t)j * NN];
      bpre[8 + j] = p1[(size_t)j * NN];
    }
  }

  for (int k0 = 0; k0 < KD; k0 += 32) {
    // ---- write B(k0) from regs into swizzled LDS (2x ds_write_b128, conflict-free) ----
    {
      uintx4 lo, hi;
#pragma unroll
      for (int jj = 0; jj < 4; ++jj) {
        lo[jj] = (unsigned int)f2bf(bpre[2 * jj]) | ((unsigned int)f2bf(bpre[2 * jj + 1]) << 16);
        hi[jj] = (unsigned int)f2bf(bpre[8 + 2 * jj]) | ((unsigned int)f2bf(bpre[8 + 2 * jj + 1]) << 16);
      }
      *(uintx4*)bdst0 = lo;
      *(uintx4*)bdst1 = hi;
    }
    // ---- stage A(k0) via global_load_lds (unchanged) ----
#pragma unroll
    for (int i = 0; i < 2; ++i) {
      int chw = i * 256 + wv * 64;          // wave-uniform chunk base
      int ch = chw + lane;
      int r = ch >> 2;                      // tile row
      int cbs = (ch & 3) ^ ((r >> 1) & 3);  // swizzled global 16B-block
      async16(&Ae[(size_t)(m0 + r) * KD + k0 + cbs * 8], &As[chw * 8]);
    }
    // ---- prefetch B(k0+32) into regs (latency hides under the barrier's vmcnt drain) ----
    {
      int kp = k0 + 32;
      if (kp >= KD) kp = 0;                 // last iter: harmless in-bounds dummy load
      const float* p0 = bsrc + (size_t)(kp + cb0 * 8) * NN;
      const float* p1 = bsrc + (size_t)(kp + cb0 * 8 + 16) * NN;
#pragma unroll
      for (int j = 0; j < 8; ++j) {
        bpre[j]     = p0[(size_t)j * NN];
        bpre[8 + j] = p1[(size_t)j * NN];
      }
    }
    __syncthreads();
    bf16x8 af[4], bfr[4];
#pragma unroll
    for (int mt = 0; mt < 4; ++mt)
      af[mt] = *(const bf16x8*)(&As[(wm + mt * 16 + mrow) * 32 + kb]);
#pragma unroll
    for (int nt = 0; nt < 4; ++nt)
      bfr[nt] = *(const bf16x8*)(&Bs[(wn + nt * 16 + mrow) * 32 + kb]);
#pragma unroll
    for (int mt = 0; mt < 4; ++mt)
#pragma unroll
      for (int nt = 0; nt < 4; ++nt)
        acc[mt][nt] = __builtin_amdgcn_mfma_f32_16x16x32_bf16(af[mt], bfr[nt], acc[mt][nt], 0, 0, 0);
    __syncthreads();
  }
  // epilogue: C/D layout col=lane&15, row=(lane>>4)*4+reg
  int crow = (lane >> 4) * 4;
  int ccol = lane & 15;
#pragma unroll
  for (int mt = 0; mt < 4; ++mt)
#pragma unroll
    for (int nt = 0; nt < 4; ++nt)
#pragma unroll
      for (int r = 0; r < 4; ++r) {
        float v = acc[mt][nt][r];
        if (GELU) v = 0.5f * v * (1.f + erff(v * 0.70710678118654752f));
        Ce[(size_t)(m0 + wm + mt * 16 + crow + r) * NN + (n0 + wn + nt * 16 + ccol)] = f2bf(v);
      }
}

// ---------------- Combine: out[t] = sum_k w_k * EO[e_k][rank_k]  (+ fused losses) ----------------
__global__ void combine_kernel(const unsigned short* __restrict__ EO,
                               const int* __restrict__ top1, const int* __restrict__ top2,
                               const float* __restrict__ p0, const float* __restrict__ p1,
                               const int* __restrict__ rank0, const int* __restrict__ rank1,
                               const float* __restrict__ probsum, const float* __restrict__ zsum,
                               const int* __restrict__ cntk, float* __restrict__ out) {
  int t = blockIdx.x;
  int d = threadIdx.x * 4;
  float a0 = 0.f, a1 = 0.f, a2 = 0.f, a3 = 0.f;
  int r0 = rank0[t];
  if (r0 >= 0) {
    float w = p0[t];
    ushort4 v = *(const ushort4*)(EO + ((size_t)top1[t] * CAP + r0) * D_DIM + d);
    a0 += w * bf2f(v.x); a1 += w * bf2f(v.y); a2 += w * bf2f(v.z); a3 += w * bf2f(v.w);
  }
  int r1 = rank1[t];
  if (r1 >= 0) {
    float w = p1[t];
    ushort4 v = *(const ushort4*)(EO + ((size_t)top2[t] * CAP + r1) * D_DIM + d);
    a0 += w * bf2f(v.x); a1 += w * bf2f(v.y); a2 += w * bf2f(v.z); a3 += w * bf2f(v.w);
  }
  float4 o; o.x = a0; o.y = a1; o.z = a2; o.w = a3;
  *(float4*)(out + (size_t)t * D_DIM + d) = o;
  if (t == 0 && threadIdx.x == 0) {        // fused finalize (scan already completed)
    float lb = 0.f;
    for (int e = 0; e < E_EXP; ++e)
      lb += (probsum[e] / (float)T_TOK) * ((float)cntk[e] / (float)(T_TOK * KSEL));
    out[(size_t)T_TOK * D_DIM] = lb * (float)E_EXP;
    out[(size_t)T_TOK * D_DIM + 1] = zsum[0] / (float)T_TOK;
  }
}

extern "C" void kernel_launch(void* const* d_in, const int* in_sizes, int n_in,
                              void* d_out, int out_size, void* d_ws, size_t ws_size,
                              hipStream_t stream) {
  const float* x = (const float*)d_in[0];
  const float* w_gate = (const float*)d_in[1];
  const float* w_fc = (const float*)d_in[2];
  const float* w_proj = (const float*)d_in[3];
  float* out = (float*)d_out;
  char* ws = (char*)d_ws;

  float* probsum = (float*)(ws + 0);
  float* zsum    = (float*)(ws + 32);
  int*   cntk    = (int*)(ws + 64);
  int*   top1    = (int*)(ws + 4096);
  int*   top2    = (int*)(ws + 20480);
  float* p0      = (float*)(ws + 36864);
  float* p1      = (float*)(ws + 53248);
  int*   rank0   = (int*)(ws + 69632);
  int*   rank1   = (int*)(ws + 86016);
  int*   slot    = (int*)(ws + 102400);                 // 40 KB -> ends 143360
  float* lz_part = (float*)(ws + 143360);               // 4 KB  -> ends 147456
  float* lps_part= (float*)(ws + 147456);               // 32 KB -> ends 180224
  unsigned short* batch = (unsigned short*)(ws + 262144);                        // 20.97 MB
  unsigned short* H     = (unsigned short*)(ws + 262144 + 20971520);             // 83.9 MB
  unsigned short* EO    = (unsigned short*)(ws + 262144 + 20971520 + 83886080);  // 20.97 MB

  router_kernel<<<T_TOK / 4, 256, 0, stream>>>(x, w_gate, top1, top2, p0, p1, lps_part, lz_part);
  scan_kernel<<<1, 256, 0, stream>>>(top1, top2, lps_part, lz_part,
                                     rank0, rank1, slot, cntk, probsum, zsum);
  dispatch_kernel<<<E_EXP * CAP, 256, 0, stream>>>(x, slot, batch);

  // GEMM1: H[c][h] = batch[c][d] * w_fc[d][h]   (B read directly from fp32 [D][HID])
  gemm_fused<D_DIM, HID_DIM, 4, true><<<8 * (HID_DIM / 128 / 4) * (CAP / 128) * 4, 256, 0, stream>>>(
      batch, w_fc, H, cntk);

  // GEMM2: EO[c][d] = H[c][h] * w_proj[h][d]    (B read directly from fp32 [HID][D])
  gemm_fused<HID_DIM, D_DIM, 2, false><<<8 * (D_DIM / 128 / 2) * (CAP / 128) * 2, 256, 0, stream>>>(
      H, w_proj, EO, cntk);

  combine_kernel<<<T_TOK, 256, 0, stream>>>(EO, top1, top2, p0, p1, rank0, rank1,
                                            probsum, zsum, cntk, out);
}